// Round 3
// baseline (797.883 us; speedup 1.0000x reference)
//
#include <hip/hip_runtime.h>

#define NPART 62
#define M     256
#define DD    256
#define NPOS  8
#define NNEG  248
#define MARG  0.2f
#define NBLK  496          // 62 parts x 8 anchor-tiles of 32
#define REC   512

#define OFF_HARD 15376     // 62*248
#define OFF_MD   15438
#define OFF_FN   15439

__global__ __launch_bounds__(256, 3) void triplet_main(
    const float* __restrict__ F, const int* __restrict__ label, float* __restrict__ ws)
{
    // region: staging tile [256 rows][32 k] floats (32KB), later reused as dist[32][256]
    __shared__ __align__(16) float region[8192];
    __shared__ float x2s[M];
    __shared__ float fullS[4][NNEG];
    __shared__ float fullC[4][NNEG];
    __shared__ float posbuf[4][NPOS];
    __shared__ float wred[8];

    const int bx   = blockIdx.x;
    const int p    = bx >> 3;
    const int ib   = (bx & 7) * 32;      // anchor base within part
    const int t    = threadIdx.x;
    const int lane = t & 63;
    const int w    = t >> 6;             // wave 0..3

    const float* Fp = F + (size_t)p * (M * DD);

    // ---- staging precompute: global_load_lds, pre-swizzled source (q ^= (row>>2)&7) ----
    int soff[8];
#pragma unroll
    for (int i = 0; i < 8; ++i) {
        int row = (i * 4 + w) * 8 + (lane >> 3);
        int q   = (lane & 7) ^ ((row >> 2) & 7);
        soff[i] = row * 256 + q * 4;
    }

    // ---- micro-tile: wave w owns anchor rows ib+w*8..+7; each lane cols lane*4..+3 ----
    const int j0  = lane * 4;
    const int bsw = lane & 7;            // ((j0+s)>>2)&7 == lane&7 for s<4
    int arow[8], asw[8];
#pragma unroll
    for (int r = 0; r < 8; ++r) {
        arow[r] = ib + w * 8 + r;
        asw[r]  = (arow[r] >> 2) & 7;    // wave-uniform
    }

    float acc[8][4];
#pragma unroll
    for (int r = 0; r < 8; ++r)
#pragma unroll
        for (int s = 0; s < 4; ++s) acc[r][s] = 0.f;
    float x2p[4] = {0.f, 0.f, 0.f, 0.f};

    for (int kt = 0; kt < 8; ++kt) {
        if (kt) __syncthreads();         // all waves done reading previous tile
#pragma unroll
        for (int i = 0; i < 8; ++i) {
            __builtin_amdgcn_global_load_lds(
                (const __attribute__((address_space(1))) void*)(Fp + soff[i] + kt * 32),
                (__attribute__((address_space(3))) void*)&region[(i * 4 + w) * 256],
                16, 0, 0);
        }
        __syncthreads();                 // vmcnt drained before barrier -> tile visible

#pragma unroll
        for (int k4 = 0; k4 < 8; ++k4) {
            float4 a[8], b[4];
#pragma unroll
            for (int s = 0; s < 4; ++s)
                b[s] = *(const float4*)&region[(j0 + s) * 32 + ((k4 ^ bsw) << 2)];
#pragma unroll
            for (int r = 0; r < 8; ++r)
                a[r] = *(const float4*)&region[arow[r] * 32 + ((k4 ^ asw[r]) << 2)];
#pragma unroll
            for (int r = 0; r < 8; ++r)
#pragma unroll
                for (int s = 0; s < 4; ++s)
                    acc[r][s] += a[r].x * b[s].x + a[r].y * b[s].y +
                                 a[r].z * b[s].z + a[r].w * b[s].w;
            if (w == 0) {                // wave-uniform: wave 0 accumulates col x^2
#pragma unroll
                for (int s = 0; s < 4; ++s)
                    x2p[s] += b[s].x * b[s].x + b[s].y * b[s].y +
                              b[s].z * b[s].z + b[s].w * b[s].w;
            }
        }
    }

    if (w == 0) {
#pragma unroll
        for (int s = 0; s < 4; ++s) x2s[j0 + s] = x2p[s];
    }
    __syncthreads();   // x2s visible; all waves done with stage buffer

    // dist tile: wave w writes its own 8 rows (dist[32][256] overlays region)
#pragma unroll
    for (int r = 0; r < 8; ++r) {
        int ia = w * 8 + r;
        float xi = x2s[ib + ia];
        float dv[4];
#pragma unroll
        for (int s = 0; s < 4; ++s) {
            float d2 = xi + x2s[j0 + s] - 2.f * acc[r][s];
            dv[s] = sqrtf(fmaxf(d2, 0.f) + 1e-12f);
        }
        *(float4*)&region[ia * 256 + j0] = make_float4(dv[0], dv[1], dv[2], dv[3]);
    }

    // ---- mining: wave-private (wave w owns anchors w*8..w*8+7) ----
    int llab[4];
#pragma unroll
    for (int ch = 0; ch < 4; ++ch) llab[ch] = label[p * M + ch * 64 + lane];

    for (int idx = lane; idx < NNEG; idx += 64) { fullS[w][idx] = 0.f; fullC[w][idx] = 0.f; }

    const unsigned long long lmask = (1ull << lane) - 1ull;
    float hardAcc = 0.f, rowSum = 0.f;

    for (int a = 0; a < 8; ++a) {
        const int ii = w * 8 + a;
        const int li = label[p * M + ib + ii];   // wave-uniform
        int runMatch = 0;
        float negmin = 3.4e38f;
        float ndv[4]; int nqv[4]; int nval[4];
#pragma unroll
        for (int ch = 0; ch < 4; ++ch) {
            const int j = ch * 64 + lane;
            float d = region[ii * 256 + j];
            bool match = (llab[ch] == li);
            unsigned long long bal = __ballot(match);
            int posRank = runMatch + __popcll(bal & lmask);
            if (match) {
                if (posRank < NPOS) posbuf[w][posRank] = d;
                nval[ch] = 0; ndv[ch] = 0.f; nqv[ch] = 0;
            } else {
                ndv[ch] = d; nqv[ch] = j - posRank; nval[ch] = 1;
                negmin = fminf(negmin, d);
            }
            runMatch += __popcll(bal);
            rowSum += d;
        }
        asm volatile("s_waitcnt lgkmcnt(0)" ::: "memory");  // same-wave posbuf drain

        float maxpos = posbuf[w][0];
#pragma unroll
        for (int pp = 1; pp < NPOS; ++pp) maxpos = fmaxf(maxpos, posbuf[w][pp]);
#pragma unroll
        for (int off = 32; off >= 1; off >>= 1)
            negmin = fminf(negmin, __shfl_xor(negmin, off));
        hardAcc += fmaxf(MARG + maxpos - negmin, 0.f);

#pragma unroll
        for (int ch = 0; ch < 4; ++ch) {
            if (nval[ch]) {
                float dneg = ndv[ch]; int q = nqv[ch];
                float s = 0.f, cnt = 0.f;
#pragma unroll
                for (int pp = 0; pp < NPOS; ++pp) {
                    float v = MARG + posbuf[w][pp] - dneg;
                    if (v > 0.f) { s += v; cnt += 1.f; }
                }
                fullS[w][q] += s;   // per-wave private; q distinct per lane
                fullC[w][q] += cnt;
            }
        }
    }

    // block reductions -> ws partial record
#pragma unroll
    for (int off = 32; off >= 1; off >>= 1) rowSum += __shfl_xor(rowSum, off);
    if (lane == 0) { wred[w] = hardAcc; wred[4 + w] = rowSum; }
    __syncthreads();

    float* rec = ws + (size_t)bx * REC;
    if (t < NNEG) {
        float s = 0.f, c = 0.f;
#pragma unroll
        for (int v = 0; v < 4; ++v) { s += fullS[v][t]; c += fullC[v][t]; }
        rec[t] = s;
        rec[NNEG + t] = c;
    }
    if (t == 0) {
        rec[496] = wred[0] + wred[1] + wred[2] + wred[3];
        rec[497] = wred[4] + wred[5] + wred[6] + wred[7];
    }
}

__global__ __launch_bounds__(256) void triplet_finalize1(const float* __restrict__ ws,
                                                         float* __restrict__ out,
                                                         float* __restrict__ wsP)
{
    const int p = blockIdx.x;
    const int t = threadIdx.x;
    if (t < NNEG) {
        float s = 0.f, c = 0.f;
        for (int a = 0; a < 8; ++a) {
            const float* rec = ws + (size_t)(p * 8 + a) * REC;
            s += rec[t];
            c += rec[NNEG + t];
        }
        out[p * NNEG + t]          = s / (c + 1e-6f);
        out[OFF_FN + p * NNEG + t] = c;
    }
    if (t == 0) {
        float h = 0.f, ds = 0.f;
        for (int a = 0; a < 8; ++a) {
            const float* rec = ws + (size_t)(p * 8 + a) * REC;
            h  += rec[496];
            ds += rec[497];
        }
        out[OFF_HARD + p] = h * (1.0f / 256.0f);
        wsP[p] = ds;
    }
}

__global__ void triplet_finalize2(const float* __restrict__ wsP, float* __restrict__ out)
{
    int t = threadIdx.x;
    float v = (t < NPART) ? wsP[t] : 0.f;
#pragma unroll
    for (int off = 32; off >= 1; off >>= 1) v += __shfl_xor(v, off);
    if (t == 0) out[OFF_MD] = v / (float)((size_t)NPART * M * M);
}

extern "C" void kernel_launch(void* const* d_in, const int* in_sizes, int n_in,
                              void* d_out, int out_size, void* d_ws, size_t ws_size,
                              hipStream_t stream)
{
    const float* F     = (const float*)d_in[0];
    const int*   label = (const int*)d_in[1];
    float*       ws    = (float*)d_ws;
    float*       out   = (float*)d_out;
    float*       wsP   = ws + (size_t)NBLK * REC;

    triplet_main<<<dim3(NBLK), dim3(256), 0, stream>>>(F, label, ws);
    triplet_finalize1<<<dim3(NPART), dim3(256), 0, stream>>>(ws, out, wsP);
    triplet_finalize2<<<dim3(1), dim3(64), 0, stream>>>(wsP, out);
}

// Round 4
// 336.626 us; speedup vs baseline: 2.3702x; 2.3702x over previous
//
#include <hip/hip_runtime.h>

#define NPART 62
#define M     256
#define DD    256
#define NPOS  8
#define NNEG  248
#define MARG  0.2f
#define REC   512

// ---- two-kernel path ws layout (floats) ----
#define DIST_F  (NPART * M * M)            // 4,063,232
#define NBLK_B  (NPART * 16)               // 992 mining blocks
#define R0      DIST_F                     // recs
#define P0      (R0 + NBLK_B * REC)        // per-part dist sums
#define X0      (P0 + NPART)               // x2 array (62*256)
#define WS_NEED ((size_t)(X0 + NPART * M) * 4)

// ---- fallback (round-1) layout ----
#define FB_NBLK 496

#define OFF_HARD 15376
#define OFF_MD   15438
#define OFF_FN   15439

// ======================= x2 kernel =======================
__global__ __launch_bounds__(256) void k_x2(const float* __restrict__ F,
                                            float* __restrict__ x2g)
{
    const int t = threadIdx.x;
    const int row = blockIdx.x * 32 + (t >> 3);
    const int q = t & 7;
    const float4* Fv = (const float4*)F;
    float s = 0.f;
#pragma unroll
    for (int j = 0; j < 8; ++j) {
        float4 v = Fv[row * 64 + j * 8 + q];
        s += v.x * v.x + v.y * v.y + v.z * v.z + v.w * v.w;
    }
    s += __shfl_xor(s, 1);
    s += __shfl_xor(s, 2);
    s += __shfl_xor(s, 4);
    if (q == 0) x2g[row] = s;
}

// ======================= GEMM + dist kernel =======================
__global__ __launch_bounds__(256) void k_gemm(const float* __restrict__ F,
                                              const float* __restrict__ x2g,
                                              float* __restrict__ distG)
{
    __shared__ __align__(16) float SA[2][128 * 36];   // 36,864 B
    __shared__ __align__(16) float SB[2][128 * 36];   // 36,864 B

    const int bxr = blockIdx.x;                       // 248 = 8*31
    const int bx  = (bxr & 7) * 31 + (bxr >> 3);      // XCD-grouped, bijective
    const int p   = bx >> 2;
    const int ri  = ((bx >> 1) & 1) * 128;
    const int rj  = (bx & 1) * 128;
    const int t   = threadIdx.x;
    const int tx  = t & 15, ty = t >> 4;

    const float4* Fv = (const float4*)(F + (size_t)p * (M * DD));

    const int srow = t >> 3;     // staging row within 32-row group
    const int sfg  = t & 7;      // k-float4 group

    float4 ra[4], rb[4];
    // prologue: load kt=0 (source pre-swizzled; LDS write linear)
#pragma unroll
    for (int i = 0; i < 4; ++i) {
        int row = i * 32 + srow;
        int q   = sfg ^ ((row >> 2) & 7);
        ra[i] = Fv[(ri + row) * 64 + q];
        rb[i] = Fv[(rj + row) * 64 + q];
    }
#pragma unroll
    for (int i = 0; i < 4; ++i) {
        int row = i * 32 + srow;
        *(float4*)&SA[0][row * 36 + sfg * 4] = ra[i];
        *(float4*)&SB[0][row * 36 + sfg * 4] = rb[i];
    }
    __syncthreads();

    float acc[8][8];
#pragma unroll
    for (int r = 0; r < 8; ++r)
#pragma unroll
        for (int c = 0; c < 8; ++c) acc[r][c] = 0.f;

    int cur = 0;
    for (int kt = 0; kt < 8; ++kt) {
        if (kt < 7) {
#pragma unroll
            for (int i = 0; i < 4; ++i) {
                int row = i * 32 + srow;
                int q   = sfg ^ ((row >> 2) & 7);
                ra[i] = Fv[(ri + row) * 64 + (kt + 1) * 8 + q];
                rb[i] = Fv[(rj + row) * 64 + (kt + 1) * 8 + q];
            }
        }
        const float* A = &SA[cur][0];
        const float* B = &SB[cur][0];
#pragma unroll
        for (int k4 = 0; k4 < 8; ++k4) {
            float4 av[8], bv[8];
#pragma unroll
            for (int r = 0; r < 8; ++r) {
                int row = ty * 8 + r;
                av[r] = *(const float4*)&A[row * 36 + ((k4 ^ ((2 * ty + (r >> 2)) & 7)) << 2)];
            }
#pragma unroll
            for (int c = 0; c < 8; ++c) {
                int col = tx * 8 + c;
                bv[c] = *(const float4*)&B[col * 36 + ((k4 ^ ((2 * tx + (c >> 2)) & 7)) << 2)];
            }
#pragma unroll
            for (int r = 0; r < 8; ++r)
#pragma unroll
                for (int c = 0; c < 8; ++c)
                    acc[r][c] += av[r].x * bv[c].x + av[r].y * bv[c].y +
                                 av[r].z * bv[c].z + av[r].w * bv[c].w;
        }
        if (kt < 7) {
#pragma unroll
            for (int i = 0; i < 4; ++i) {
                int row = i * 32 + srow;
                *(float4*)&SA[cur ^ 1][row * 36 + sfg * 4] = ra[i];
                *(float4*)&SB[cur ^ 1][row * 36 + sfg * 4] = rb[i];
            }
            __syncthreads();
            cur ^= 1;
        }
    }

    // epilogue: dist = sqrt(max(xi+xj-2dot,0)+eps) -> global
    float xi[8], xj[8];
#pragma unroll
    for (int r = 0; r < 8; ++r) xi[r] = x2g[p * M + ri + ty * 8 + r];
#pragma unroll
    for (int c = 0; c < 8; ++c) xj[c] = x2g[p * M + rj + tx * 8 + c];

#pragma unroll
    for (int r = 0; r < 8; ++r) {
        float dv[8];
#pragma unroll
        for (int c = 0; c < 8; ++c) {
            float d2 = xi[r] + xj[c] - 2.f * acc[r][c];
            dv[c] = sqrtf(fmaxf(d2, 0.f) + 1e-12f);
        }
        size_t base = ((size_t)(p * M + ri + ty * 8 + r) << 8) + rj + tx * 8;
        *(float4*)&distG[base]     = make_float4(dv[0], dv[1], dv[2], dv[3]);
        *(float4*)&distG[base + 4] = make_float4(dv[4], dv[5], dv[6], dv[7]);
    }
}

// ======================= mining kernel =======================
__global__ __launch_bounds__(256) void k_mine(const float* __restrict__ distG,
                                              const int* __restrict__ label,
                                              float* __restrict__ recs)
{
    __shared__ float fullS[4][NNEG];
    __shared__ float fullC[4][NNEG];
    __shared__ float posbuf[4][NPOS];
    __shared__ float wred[8];

    const int bxr  = blockIdx.x;                      // 992 = 8*124
    const int bx   = (bxr & 7) * 124 + (bxr >> 3);    // XCD-grouped, bijective
    const int p    = bx >> 4;
    const int base = (bx & 15) * 16;
    const int t    = threadIdx.x;
    const int lane = t & 63;
    const int w    = t >> 6;

    int llab[4];
#pragma unroll
    for (int ch = 0; ch < 4; ++ch) llab[ch] = label[p * M + ch * 64 + lane];

    for (int idx = lane; idx < NNEG; idx += 64) { fullS[w][idx] = 0.f; fullC[w][idx] = 0.f; }

    const unsigned long long lmask = (1ull << lane) - 1ull;
    float hardAcc = 0.f, rowSum = 0.f;

    for (int a = 0; a < 4; ++a) {
        const int ii = base + w * 4 + a;
        const int li = label[p * M + ii];   // wave-uniform
        const float* drow = distG + ((size_t)p * M + ii) * M;
        int runMatch = 0;
        float negmin = 3.4e38f;
        float ndv[4]; int nqv[4]; int nval[4];
#pragma unroll
        for (int ch = 0; ch < 4; ++ch) {
            const int j = ch * 64 + lane;
            float d = drow[j];
            bool match = (llab[ch] == li);
            unsigned long long bal = __ballot(match);
            int posRank = runMatch + __popcll(bal & lmask);
            if (match) {
                if (posRank < NPOS) posbuf[w][posRank] = d;
                nval[ch] = 0; ndv[ch] = 0.f; nqv[ch] = 0;
            } else {
                ndv[ch] = d; nqv[ch] = j - posRank; nval[ch] = 1;
                negmin = fminf(negmin, d);
            }
            runMatch += __popcll(bal);
            rowSum += d;
        }
        asm volatile("s_waitcnt lgkmcnt(0)" ::: "memory");  // same-wave posbuf drain

        float maxpos = posbuf[w][0];
#pragma unroll
        for (int pp = 1; pp < NPOS; ++pp) maxpos = fmaxf(maxpos, posbuf[w][pp]);
#pragma unroll
        for (int off = 32; off >= 1; off >>= 1)
            negmin = fminf(negmin, __shfl_xor(negmin, off));
        hardAcc += fmaxf(MARG + maxpos - negmin, 0.f);

#pragma unroll
        for (int ch = 0; ch < 4; ++ch) {
            if (nval[ch]) {
                float dneg = ndv[ch]; int q = nqv[ch];
                float s = 0.f, cnt = 0.f;
#pragma unroll
                for (int pp = 0; pp < NPOS; ++pp) {
                    float v = MARG + posbuf[w][pp] - dneg;
                    if (v > 0.f) { s += v; cnt += 1.f; }
                }
                fullS[w][q] += s;
                fullC[w][q] += cnt;
            }
        }
    }

#pragma unroll
    for (int off = 32; off >= 1; off >>= 1) rowSum += __shfl_xor(rowSum, off);
    if (lane == 0) { wred[w] = hardAcc; wred[4 + w] = rowSum; }
    __syncthreads();

    float* rec = recs + (size_t)bx * REC;
    if (t < NNEG) {
        float s = 0.f, c = 0.f;
#pragma unroll
        for (int v = 0; v < 4; ++v) { s += fullS[v][t]; c += fullC[v][t]; }
        rec[t] = s;
        rec[NNEG + t] = c;
    }
    if (t == 0) {
        rec[496] = wred[0] + wred[1] + wred[2] + wred[3];
        rec[497] = wred[4] + wred[5] + wred[6] + wred[7];
    }
}

// ======================= finalize =======================
__global__ __launch_bounds__(256) void k_fin1(const float* __restrict__ recs,
                                              float* __restrict__ out,
                                              float* __restrict__ wsP)
{
    const int p = blockIdx.x;
    const int t = threadIdx.x;
    if (t < NNEG) {
        float s = 0.f, c = 0.f;
        for (int a = 0; a < 16; ++a) {
            const float* rec = recs + (size_t)(p * 16 + a) * REC;
            s += rec[t];
            c += rec[NNEG + t];
        }
        out[p * NNEG + t]          = s / (c + 1e-6f);
        out[OFF_FN + p * NNEG + t] = c;
    }
    if (t == 0) {
        float h = 0.f, ds = 0.f;
        for (int a = 0; a < 16; ++a) {
            const float* rec = recs + (size_t)(p * 16 + a) * REC;
            h  += rec[496];
            ds += rec[497];
        }
        out[OFF_HARD + p] = h * (1.0f / 256.0f);
        wsP[p] = ds;
    }
}

__global__ void k_fin2(const float* __restrict__ wsP, float* __restrict__ out)
{
    int t = threadIdx.x;
    float v = (t < NPART) ? wsP[t] : 0.f;
#pragma unroll
    for (int off = 32; off >= 1; off >>= 1) v += __shfl_xor(v, off);
    if (t == 0) out[OFF_MD] = v / (float)((size_t)NPART * M * M);
}

// ======================= fallback: proven round-1 fused path =======================
__global__ __launch_bounds__(256) void fb_main(
    const float* __restrict__ F, const int* __restrict__ label, float* __restrict__ ws)
{
    __shared__ __align__(16) float region[256 * 36];
    __shared__ float x2s[M];
    __shared__ int   lab[M];
    __shared__ float posbuf[4][NPOS];
    __shared__ float fullS[4][NNEG];
    __shared__ float fullC[4][NNEG];
    __shared__ float wred[8];

    const int bx = blockIdx.x;
    const int p  = bx >> 3;
    const int ib = (bx & 7) * 32;
    const int t  = threadIdx.x;

    lab[t] = label[p * M + t];
    for (int idx = t; idx < 4 * NNEG; idx += 256) {
        (&fullS[0][0])[idx] = 0.f;
        (&fullC[0][0])[idx] = 0.f;
    }
    __syncthreads();

    const float4* Fv = (const float4*)(F + (size_t)p * (M * DD));

    float acc[4][8];
#pragma unroll
    for (int r = 0; r < 4; ++r)
#pragma unroll
        for (int c = 0; c < 8; ++c) acc[r][c] = 0.f;

    float x2loc = 0.f;
    const int tc = t & 31;
    const int tg = t >> 5;

    for (int kt = 0; kt < 8; ++kt) {
#pragma unroll
        for (int w = 0; w < 8; ++w) {
            int ch = w * 256 + t;
            int r  = ch >> 3;
            int q  = ch & 7;
            float4 v = Fv[r * 64 + kt * 8 + q];
            float* dst = &region[r * 36 + q * 4];
            dst[0] = v.x; dst[1] = v.y; dst[2] = v.z; dst[3] = v.w;
        }
        __syncthreads();
#pragma unroll
        for (int k4 = 0; k4 < 8; ++k4) {
            float4 b = *(const float4*)&region[t * 36 + k4 * 4];
            x2loc += b.x * b.x + b.y * b.y + b.z * b.z + b.w * b.w;
        }
#pragma unroll
        for (int k4 = 0; k4 < 8; ++k4) {
            float4 a4[4], b4[8];
#pragma unroll
            for (int r = 0; r < 4; ++r)
                a4[r] = *(const float4*)&region[(ib + tg * 4 + r) * 36 + k4 * 4];
#pragma unroll
            for (int c = 0; c < 8; ++c)
                b4[c] = *(const float4*)&region[(tc + 32 * c) * 36 + k4 * 4];
#pragma unroll
            for (int r = 0; r < 4; ++r)
#pragma unroll
                for (int c = 0; c < 8; ++c)
                    acc[r][c] += a4[r].x * b4[c].x + a4[r].y * b4[c].y +
                                 a4[r].z * b4[c].z + a4[r].w * b4[c].w;
        }
        __syncthreads();
    }

    x2s[t] = x2loc;
    __syncthreads();

#pragma unroll
    for (int r = 0; r < 4; ++r) {
        int ii = tg * 4 + r;
        float xi = x2s[ib + ii];
#pragma unroll
        for (int c = 0; c < 8; ++c) {
            int j = tc + 32 * c;
            float d2 = xi + x2s[j] - 2.f * acc[r][c];
            region[ii * M + j] = sqrtf(fmaxf(d2, 0.f) + 1e-12f);
        }
    }
    __syncthreads();

    const int lane = t & 63;
    const int w    = t >> 6;
    const unsigned long long lmask = (1ull << lane) - 1ull;

    float hardAcc = 0.f;
    float rowSum  = 0.f;

    for (int a = 0; a < 8; ++a) {
        int ii = w * 8 + a;
        int li = lab[ib + ii];
        int runMatch = 0;
        float negmin = 3.4e38f;
        float ndv[4]; int nqv[4]; int nval[4];
#pragma unroll
        for (int ch = 0; ch < 4; ++ch) {
            int j = ch * 64 + lane;
            float d = region[ii * M + j];
            bool match = (lab[j] == li);
            unsigned long long bal = __ballot(match);
            int prefix  = __popcll(bal & lmask);
            int posRank = runMatch + prefix;
            if (match) {
                if (posRank < NPOS) posbuf[w][posRank] = d;
                nval[ch] = 0; ndv[ch] = 0.f; nqv[ch] = 0;
            } else {
                ndv[ch] = d; nqv[ch] = j - posRank; nval[ch] = 1;
                negmin = fminf(negmin, d);
            }
            runMatch += __popcll(bal);
            rowSum += d;
        }
        __syncthreads();

        float maxpos = posbuf[w][0];
#pragma unroll
        for (int pp = 1; pp < NPOS; ++pp) maxpos = fmaxf(maxpos, posbuf[w][pp]);
#pragma unroll
        for (int off = 32; off >= 1; off >>= 1)
            negmin = fminf(negmin, __shfl_xor(negmin, off));
        hardAcc += fmaxf(MARG + maxpos - negmin, 0.f);

#pragma unroll
        for (int ch = 0; ch < 4; ++ch) {
            if (nval[ch]) {
                float dneg = ndv[ch]; int q = nqv[ch];
                float s = 0.f, cnt = 0.f;
#pragma unroll
                for (int pp = 0; pp < NPOS; ++pp) {
                    float v = MARG + posbuf[w][pp] - dneg;
                    if (v > 0.f) { s += v; cnt += 1.f; }
                }
                fullS[w][q] += s;
                fullC[w][q] += cnt;
            }
        }
        __syncthreads();
    }

#pragma unroll
    for (int off = 32; off >= 1; off >>= 1) rowSum += __shfl_xor(rowSum, off);
    if (lane == 0) { wred[w] = hardAcc; wred[4 + w] = rowSum; }
    __syncthreads();

    float* rec = ws + (size_t)bx * REC;
    if (t < NNEG) {
        float s = fullS[0][t] + fullS[1][t] + fullS[2][t] + fullS[3][t];
        float c = fullC[0][t] + fullC[1][t] + fullC[2][t] + fullC[3][t];
        rec[t] = s;
        rec[NNEG + t] = c;
    }
    if (t == 0) {
        rec[496] = wred[0] + wred[1] + wred[2] + wred[3];
        rec[497] = wred[4] + wred[5] + wred[6] + wred[7];
    }
}

__global__ __launch_bounds__(256) void fb_fin1(const float* __restrict__ ws,
                                               float* __restrict__ out,
                                               float* __restrict__ wsP)
{
    const int p = blockIdx.x;
    const int t = threadIdx.x;
    if (t < NNEG) {
        float s = 0.f, c = 0.f;
        for (int a = 0; a < 8; ++a) {
            const float* rec = ws + (size_t)(p * 8 + a) * REC;
            s += rec[t];
            c += rec[NNEG + t];
        }
        out[p * NNEG + t]          = s / (c + 1e-6f);
        out[OFF_FN + p * NNEG + t] = c;
    }
    if (t == 0) {
        float h = 0.f, ds = 0.f;
        for (int a = 0; a < 8; ++a) {
            const float* rec = ws + (size_t)(p * 8 + a) * REC;
            h  += rec[496];
            ds += rec[497];
        }
        out[OFF_HARD + p] = h * (1.0f / 256.0f);
        wsP[p] = ds;
    }
}

// ======================= launch =======================
extern "C" void kernel_launch(void* const* d_in, const int* in_sizes, int n_in,
                              void* d_out, int out_size, void* d_ws, size_t ws_size,
                              hipStream_t stream)
{
    const float* F     = (const float*)d_in[0];
    const int*   label = (const int*)d_in[1];
    float*       ws    = (float*)d_ws;
    float*       out   = (float*)d_out;

    if (ws_size >= WS_NEED) {
        float* distG = ws;
        float* recs  = ws + R0;
        float* wsP   = ws + P0;
        float* x2g   = ws + X0;
        k_x2  <<<dim3(496),    dim3(256), 0, stream>>>(F, x2g);
        k_gemm<<<dim3(248),    dim3(256), 0, stream>>>(F, x2g, distG);
        k_mine<<<dim3(NBLK_B), dim3(256), 0, stream>>>(distG, label, recs);
        k_fin1<<<dim3(NPART),  dim3(256), 0, stream>>>(recs, out, wsP);
        k_fin2<<<dim3(1),      dim3(64),  0, stream>>>(wsP, out);
    } else {
        float* wsP = ws + (size_t)FB_NBLK * REC;
        fb_main<<<dim3(FB_NBLK), dim3(256), 0, stream>>>(F, label, ws);
        fb_fin1<<<dim3(NPART),   dim3(256), 0, stream>>>(ws, out, wsP);
        k_fin2 <<<dim3(1),       dim3(64),  0, stream>>>(wsP, out);
    }
}

// Round 5
// 43.424 us; speedup vs baseline: 18.3742x; 7.7520x over previous
//
#include <hip/hip_runtime.h>

#define NPART 62
#define M     256
#define DD    256
#define NPOS  8
#define NNEG  248
#define MARG  0.2f
#define REC   512

// ---- ws layout (float units) ----
#define FRAG_F 4063232                    // Ffrag: 8,126,464 halfs = 4,063,232 floats
#define X0     FRAG_F                     // x2 (62*256 floats)
#define R0     (X0 + NPART * M)           // recs (496*512)
#define P0     (R0 + 496 * REC)           // per-part dist sums (62)
#define WS_NEED ((size_t)(P0 + NPART) * 4)

#define OFF_HARD 15376
#define OFF_MD   15438
#define OFF_FN   15439

typedef _Float16 f16x8 __attribute__((ext_vector_type(8)));
typedef float    f32x4 __attribute__((ext_vector_type(4)));

// ======================= split kernel: fp32 -> frag-layout fp16 hi/lo + x2 =======================
// Ffrag half-index: ((((p*8+s)*16 + tile)*2 + h)*64 + l)*8 + j
//   s = k>>5, g = (k>>3)&3, j = k&7, tile = row>>4, l = (row&15) + 16*g
__global__ __launch_bounds__(256) void k_split(const float* __restrict__ F,
                                               _Float16* __restrict__ Ffrag,
                                               float* __restrict__ x2g)
{
    const int b   = blockIdx.x;          // 992 = 62 parts * 16 tiles
    const int p   = b >> 4;
    const int t16 = b & 15;
    const int t   = threadIdx.x;
    const int row16 = t >> 4;            // row within tile
    const int kc    = t & 15;            // 16-k chunk

    const int row = t16 * 16 + row16;
    const float4* src = (const float4*)(F + ((size_t)(p * M + row) * DD) + kc * 16);

    float v[16];
#pragma unroll
    for (int i = 0; i < 4; ++i) {
        float4 q = src[i];
        v[i * 4 + 0] = q.x; v[i * 4 + 1] = q.y; v[i * 4 + 2] = q.z; v[i * 4 + 3] = q.w;
    }

    float s2 = 0.f;
#pragma unroll
    for (int i = 0; i < 16; ++i) s2 += v[i] * v[i];
    s2 += __shfl_xor(s2, 1);
    s2 += __shfl_xor(s2, 2);
    s2 += __shfl_xor(s2, 4);
    s2 += __shfl_xor(s2, 8);
    if (kc == 0) x2g[p * M + row] = s2;

#pragma unroll
    for (int b2 = 0; b2 < 2; ++b2) {
        const int o = kc * 2 + b2;       // global k-octet
        const int s = o >> 2;
        const int g = o & 3;
        const int l = row16 + 16 * g;
        f16x8 hv, lv;
#pragma unroll
        for (int j = 0; j < 8; ++j) {
            float x = v[b2 * 8 + j];
            _Float16 h = (_Float16)x;
            hv[j] = h;
            lv[j] = (_Float16)(x - (float)h);
        }
        size_t base = ((((size_t)(p * 8 + s) * 16 + t16) * 2 + 0) * 64 + l) * 8;
        *(f16x8*)(Ffrag + base)         = hv;   // h=0
        *(f16x8*)(Ffrag + base + 512)   = lv;   // h=1 (+1*64*8)
    }
}

// ======================= fused dist (MFMA) + mining =======================
#define PITCH 258
__global__ __launch_bounds__(256) void k_dist(const _Float16* __restrict__ Ffrag,
                                              const float* __restrict__ x2g,
                                              const int* __restrict__ label,
                                              float* __restrict__ recs)
{
    __shared__ __align__(16) float region[32 * PITCH];   // dist tile, 33,024 B
    __shared__ float fullS[4][NNEG];
    __shared__ float fullC[4][NNEG];
    __shared__ float posbuf[4][NPOS];
    __shared__ float wred[8];

    const int bxr = blockIdx.x;                       // 496 = 8 XCD * 62
    const int swz = (bxr & 7) * 62 + (bxr >> 3);      // bijective; part's 8 tiles contiguous
    const int p   = swz >> 3;
    const int ib  = (swz & 7) * 32;                   // anchor base
    const int t   = threadIdx.x;
    const int lane = t & 63;
    const int w    = t >> 6;                          // wave 0..3

    const int a0 = ib >> 4;                           // first A row-tile (of 16)

    f32x4 acc[2][4];
#pragma unroll
    for (int rt = 0; rt < 2; ++rt)
#pragma unroll
        for (int c = 0; c < 4; ++c) acc[rt][c] = (f32x4){0.f, 0.f, 0.f, 0.f};

    // ---- barrier-free MFMA K-loop: fragments straight from global (L2-hot) ----
#pragma unroll 2
    for (int s = 0; s < 8; ++s) {
        const _Float16* SB = Ffrag + (size_t)(p * 8 + s) * 16384 + lane * 8;
        f16x8 af[2][2], bf[4][2];
#pragma unroll
        for (int rt = 0; rt < 2; ++rt)
#pragma unroll
            for (int h = 0; h < 2; ++h)
                af[rt][h] = *(const f16x8*)(SB + ((a0 + rt) * 2 + h) * 512);
#pragma unroll
        for (int c = 0; c < 4; ++c)
#pragma unroll
            for (int h = 0; h < 2; ++h)
                bf[c][h] = *(const f16x8*)(SB + ((w * 4 + c) * 2 + h) * 512);
#pragma unroll
        for (int rt = 0; rt < 2; ++rt)
#pragma unroll
            for (int c = 0; c < 4; ++c) {
                acc[rt][c] = __builtin_amdgcn_mfma_f32_16x16x32_f16(af[rt][0], bf[c][0], acc[rt][c], 0, 0, 0);
                acc[rt][c] = __builtin_amdgcn_mfma_f32_16x16x32_f16(af[rt][0], bf[c][1], acc[rt][c], 0, 0, 0);
                acc[rt][c] = __builtin_amdgcn_mfma_f32_16x16x32_f16(af[rt][1], bf[c][0], acc[rt][c], 0, 0, 0);
            }
    }

    // ---- epilogue: dist -> LDS (C/D layout: col=lane&15, row=(lane>>4)*4+r) ----
    const int cbase = lane & 15;
    const int rbase = (lane >> 4) * 4;
    float xi[2][4], xj[4];
#pragma unroll
    for (int rt = 0; rt < 2; ++rt)
#pragma unroll
        for (int r = 0; r < 4; ++r)
            xi[rt][r] = x2g[p * M + ib + rt * 16 + rbase + r];
#pragma unroll
    for (int c = 0; c < 4; ++c)
        xj[c] = x2g[p * M + (w * 4 + c) * 16 + cbase];

#pragma unroll
    for (int rt = 0; rt < 2; ++rt)
#pragma unroll
        for (int c = 0; c < 4; ++c)
#pragma unroll
            for (int r = 0; r < 4; ++r) {
                float d2 = xi[rt][r] + xj[c] - 2.f * acc[rt][c][r];
                float dd = sqrtf(fmaxf(d2, 0.f) + 1e-12f);
                region[(rt * 16 + rbase + r) * PITCH + (w * 4 + c) * 16 + cbase] = dd;
            }
    __syncthreads();

    // ---- mining: wave-private (wave w owns anchors w*8..w*8+7) ----
    int llab[4];
#pragma unroll
    for (int ch = 0; ch < 4; ++ch) llab[ch] = label[p * M + ch * 64 + lane];

    for (int idx = lane; idx < NNEG; idx += 64) { fullS[w][idx] = 0.f; fullC[w][idx] = 0.f; }

    const unsigned long long lmask = (1ull << lane) - 1ull;
    float hardAcc = 0.f, rowSum = 0.f;

    for (int a = 0; a < 8; ++a) {
        const int ii = w * 8 + a;
        const int li = label[p * M + ib + ii];   // wave-uniform
        int runMatch = 0;
        float negmin = 3.4e38f;
        float ndv[4]; int nqv[4]; int nval[4];
#pragma unroll
        for (int ch = 0; ch < 4; ++ch) {
            const int j = ch * 64 + lane;
            float d = region[ii * PITCH + j];
            bool match = (llab[ch] == li);
            unsigned long long bal = __ballot(match);
            int posRank = runMatch + __popcll(bal & lmask);
            if (match) {
                if (posRank < NPOS) posbuf[w][posRank] = d;
                nval[ch] = 0; ndv[ch] = 0.f; nqv[ch] = 0;
            } else {
                ndv[ch] = d; nqv[ch] = j - posRank; nval[ch] = 1;
                negmin = fminf(negmin, d);
            }
            runMatch += __popcll(bal);
            rowSum += d;
        }
        asm volatile("s_waitcnt lgkmcnt(0)" ::: "memory");  // same-wave posbuf drain

        float maxpos = posbuf[w][0];
#pragma unroll
        for (int pp = 1; pp < NPOS; ++pp) maxpos = fmaxf(maxpos, posbuf[w][pp]);
#pragma unroll
        for (int off = 32; off >= 1; off >>= 1)
            negmin = fminf(negmin, __shfl_xor(negmin, off));
        hardAcc += fmaxf(MARG + maxpos - negmin, 0.f);

#pragma unroll
        for (int ch = 0; ch < 4; ++ch) {
            if (nval[ch]) {
                float dneg = ndv[ch]; int q = nqv[ch];
                float s = 0.f, cnt = 0.f;
#pragma unroll
                for (int pp = 0; pp < NPOS; ++pp) {
                    float v = MARG + posbuf[w][pp] - dneg;
                    if (v > 0.f) { s += v; cnt += 1.f; }
                }
                fullS[w][q] += s;   // per-wave private; q distinct per lane
                fullC[w][q] += cnt;
            }
        }
    }

#pragma unroll
    for (int off = 32; off >= 1; off >>= 1) rowSum += __shfl_xor(rowSum, off);
    if (lane == 0) { wred[w] = hardAcc; wred[4 + w] = rowSum; }
    __syncthreads();

    float* rec = recs + (size_t)swz * REC;
    if (t < NNEG) {
        float s = 0.f, c = 0.f;
#pragma unroll
        for (int v = 0; v < 4; ++v) { s += fullS[v][t]; c += fullC[v][t]; }
        rec[t] = s;
        rec[NNEG + t] = c;
    }
    if (t == 0) {
        rec[496] = wred[0] + wred[1] + wred[2] + wred[3];
        rec[497] = wred[4] + wred[5] + wred[6] + wred[7];
    }
}

// ======================= finalize =======================
__global__ __launch_bounds__(256) void k_fin1(const float* __restrict__ recs,
                                              float* __restrict__ out,
                                              float* __restrict__ wsP)
{
    const int p = blockIdx.x;
    const int t = threadIdx.x;
    if (t < NNEG) {
        float s = 0.f, c = 0.f;
        for (int a = 0; a < 8; ++a) {
            const float* rec = recs + (size_t)(p * 8 + a) * REC;
            s += rec[t];
            c += rec[NNEG + t];
        }
        out[p * NNEG + t]          = s / (c + 1e-6f);
        out[OFF_FN + p * NNEG + t] = c;
    }
    if (t == 0) {
        float h = 0.f, ds = 0.f;
        for (int a = 0; a < 8; ++a) {
            const float* rec = recs + (size_t)(p * 8 + a) * REC;
            h  += rec[496];
            ds += rec[497];
        }
        out[OFF_HARD + p] = h * (1.0f / 256.0f);
        wsP[p] = ds;
    }
}

__global__ void k_fin2(const float* __restrict__ wsP, float* __restrict__ out)
{
    int t = threadIdx.x;
    float v = (t < NPART) ? wsP[t] : 0.f;
#pragma unroll
    for (int off = 32; off >= 1; off >>= 1) v += __shfl_xor(v, off);
    if (t == 0) out[OFF_MD] = v / (float)((size_t)NPART * M * M);
}

// ======================= fallback: proven round-1 fused path =======================
__global__ __launch_bounds__(256) void fb_main(
    const float* __restrict__ F, const int* __restrict__ label, float* __restrict__ ws)
{
    __shared__ __align__(16) float region[256 * 36];
    __shared__ float x2s[M];
    __shared__ int   lab[M];
    __shared__ float posbuf[4][NPOS];
    __shared__ float fullS[4][NNEG];
    __shared__ float fullC[4][NNEG];
    __shared__ float wred[8];

    const int bx = blockIdx.x;
    const int p  = bx >> 3;
    const int ib = (bx & 7) * 32;
    const int t  = threadIdx.x;

    lab[t] = label[p * M + t];
    for (int idx = t; idx < 4 * NNEG; idx += 256) {
        (&fullS[0][0])[idx] = 0.f;
        (&fullC[0][0])[idx] = 0.f;
    }
    __syncthreads();

    const float4* Fv = (const float4*)(F + (size_t)p * (M * DD));

    float acc[4][8];
#pragma unroll
    for (int r = 0; r < 4; ++r)
#pragma unroll
        for (int c = 0; c < 8; ++c) acc[r][c] = 0.f;

    float x2loc = 0.f;
    const int tc = t & 31;
    const int tg = t >> 5;

    for (int kt = 0; kt < 8; ++kt) {
#pragma unroll
        for (int w = 0; w < 8; ++w) {
            int ch = w * 256 + t;
            int r  = ch >> 3;
            int q  = ch & 7;
            float4 v = Fv[r * 64 + kt * 8 + q];
            float* dst = &region[r * 36 + q * 4];
            dst[0] = v.x; dst[1] = v.y; dst[2] = v.z; dst[3] = v.w;
        }
        __syncthreads();
#pragma unroll
        for (int k4 = 0; k4 < 8; ++k4) {
            float4 b = *(const float4*)&region[t * 36 + k4 * 4];
            x2loc += b.x * b.x + b.y * b.y + b.z * b.z + b.w * b.w;
        }
#pragma unroll
        for (int k4 = 0; k4 < 8; ++k4) {
            float4 a4[4], b4[8];
#pragma unroll
            for (int r = 0; r < 4; ++r)
                a4[r] = *(const float4*)&region[(ib + tg * 4 + r) * 36 + k4 * 4];
#pragma unroll
            for (int c = 0; c < 8; ++c)
                b4[c] = *(const float4*)&region[(tc + 32 * c) * 36 + k4 * 4];
#pragma unroll
            for (int r = 0; r < 4; ++r)
#pragma unroll
                for (int c = 0; c < 8; ++c)
                    acc[r][c] += a4[r].x * b4[c].x + a4[r].y * b4[c].y +
                                 a4[r].z * b4[c].z + a4[r].w * b4[c].w;
        }
        __syncthreads();
    }

    x2s[t] = x2loc;
    __syncthreads();

#pragma unroll
    for (int r = 0; r < 4; ++r) {
        int ii = tg * 4 + r;
        float xi = x2s[ib + ii];
#pragma unroll
        for (int c = 0; c < 8; ++c) {
            int j = tc + 32 * c;
            float d2 = xi + x2s[j] - 2.f * acc[r][c];
            region[ii * M + j] = sqrtf(fmaxf(d2, 0.f) + 1e-12f);
        }
    }
    __syncthreads();

    const int lane = t & 63;
    const int w    = t >> 6;
    const unsigned long long lmask = (1ull << lane) - 1ull;

    float hardAcc = 0.f;
    float rowSum  = 0.f;

    for (int a = 0; a < 8; ++a) {
        int ii = w * 8 + a;
        int li = lab[ib + ii];
        int runMatch = 0;
        float negmin = 3.4e38f;
        float ndv[4]; int nqv[4]; int nval[4];
#pragma unroll
        for (int ch = 0; ch < 4; ++ch) {
            int j = ch * 64 + lane;
            float d = region[ii * M + j];
            bool match = (lab[j] == li);
            unsigned long long bal = __ballot(match);
            int prefix  = __popcll(bal & lmask);
            int posRank = runMatch + prefix;
            if (match) {
                if (posRank < NPOS) posbuf[w][posRank] = d;
                nval[ch] = 0; ndv[ch] = 0.f; nqv[ch] = 0;
            } else {
                ndv[ch] = d; nqv[ch] = j - posRank; nval[ch] = 1;
                negmin = fminf(negmin, d);
            }
            runMatch += __popcll(bal);
            rowSum += d;
        }
        __syncthreads();

        float maxpos = posbuf[w][0];
#pragma unroll
        for (int pp = 1; pp < NPOS; ++pp) maxpos = fmaxf(maxpos, posbuf[w][pp]);
#pragma unroll
        for (int off = 32; off >= 1; off >>= 1)
            negmin = fminf(negmin, __shfl_xor(negmin, off));
        hardAcc += fmaxf(MARG + maxpos - negmin, 0.f);

#pragma unroll
        for (int ch = 0; ch < 4; ++ch) {
            if (nval[ch]) {
                float dneg = ndv[ch]; int q = nqv[ch];
                float s = 0.f, cnt = 0.f;
#pragma unroll
                for (int pp = 0; pp < NPOS; ++pp) {
                    float v = MARG + posbuf[w][pp] - dneg;
                    if (v > 0.f) { s += v; cnt += 1.f; }
                }
                fullS[w][q] += s;
                fullC[w][q] += cnt;
            }
        }
        __syncthreads();
    }

#pragma unroll
    for (int off = 32; off >= 1; off >>= 1) rowSum += __shfl_xor(rowSum, off);
    if (lane == 0) { wred[w] = hardAcc; wred[4 + w] = rowSum; }
    __syncthreads();

    float* rec = ws + (size_t)bx * REC;
    if (t < NNEG) {
        float s = fullS[0][t] + fullS[1][t] + fullS[2][t] + fullS[3][t];
        float c = fullC[0][t] + fullC[1][t] + fullC[2][t] + fullC[3][t];
        rec[t] = s;
        rec[NNEG + t] = c;
    }
    if (t == 0) {
        rec[496] = wred[0] + wred[1] + wred[2] + wred[3];
        rec[497] = wred[4] + wred[5] + wred[6] + wred[7];
    }
}

// ======================= launch =======================
extern "C" void kernel_launch(void* const* d_in, const int* in_sizes, int n_in,
                              void* d_out, int out_size, void* d_ws, size_t ws_size,
                              hipStream_t stream)
{
    const float* F     = (const float*)d_in[0];
    const int*   label = (const int*)d_in[1];
    float*       ws    = (float*)d_ws;
    float*       out   = (float*)d_out;

    if (ws_size >= WS_NEED) {
        _Float16* Ffrag = (_Float16*)ws;
        float*    x2g   = ws + X0;
        float*    recs  = ws + R0;
        float*    wsP   = ws + P0;
        k_split<<<dim3(992),   dim3(256), 0, stream>>>(F, Ffrag, x2g);
        k_dist <<<dim3(496),   dim3(256), 0, stream>>>(Ffrag, x2g, label, recs);
        k_fin1 <<<dim3(NPART), dim3(256), 0, stream>>>(recs, out, wsP);
        k_fin2 <<<dim3(1),     dim3(64),  0, stream>>>(wsP, out);
    } else {
        float* wsP = ws + (size_t)496 * REC;
        fb_main<<<dim3(496),   dim3(256), 0, stream>>>(F, label, ws);
        k_fin1 <<<dim3(NPART), dim3(256), 0, stream>>>(ws, out, wsP);
        k_fin2 <<<dim3(1),     dim3(64),  0, stream>>>(wsP, out);
    }
}

// Round 6
// 40.823 us; speedup vs baseline: 19.5451x; 1.0637x over previous
//
#include <hip/hip_runtime.h>

#define NPART 62
#define M     256
#define DD    256
#define NPOS  8
#define NNEG  248
#define MARG  0.2f
#define REC   512

// ---- ws layout (float units) ----
#define FRAG_F 4063232                    // Ffrag: 8,126,464 halfs = 4,063,232 floats
#define X0     FRAG_F                     // x2 (62*256 floats)
#define R0     (X0 + NPART * M)           // recs (496*512)
#define P0     (R0 + 496 * REC)           // per-part dist sums (62)
#define WS_NEED ((size_t)(P0 + NPART) * 4)

#define OFF_HARD 15376
#define OFF_MD   15438
#define OFF_FN   15439

typedef _Float16 f16x8 __attribute__((ext_vector_type(8)));
typedef float    f32x4 __attribute__((ext_vector_type(4)));

// ======================= split kernel: fp32 -> frag-layout fp16 hi/lo + x2 =======================
// Ffrag half-index: ((((p*8+s)*16 + tile)*2 + h)*64 + l)*8 + j
//   s = k>>5, g = (k>>3)&3, j = k&7, tile = row>>4, l = (row&15) + 16*g
__global__ __launch_bounds__(256) void k_split(const float* __restrict__ F,
                                               _Float16* __restrict__ Ffrag,
                                               float* __restrict__ x2g)
{
    const int b   = blockIdx.x;          // 992 = 62 parts * 16 tiles
    const int p   = b >> 4;
    const int t16 = b & 15;
    const int t   = threadIdx.x;
    const int row16 = t >> 4;            // row within tile
    const int kc    = t & 15;            // 16-k chunk

    const int row = t16 * 16 + row16;
    const float4* src = (const float4*)(F + ((size_t)(p * M + row) * DD) + kc * 16);

    float v[16];
#pragma unroll
    for (int i = 0; i < 4; ++i) {
        float4 q = src[i];
        v[i * 4 + 0] = q.x; v[i * 4 + 1] = q.y; v[i * 4 + 2] = q.z; v[i * 4 + 3] = q.w;
    }

    float s2 = 0.f;
#pragma unroll
    for (int i = 0; i < 16; ++i) s2 += v[i] * v[i];
    s2 += __shfl_xor(s2, 1);
    s2 += __shfl_xor(s2, 2);
    s2 += __shfl_xor(s2, 4);
    s2 += __shfl_xor(s2, 8);
    if (kc == 0) x2g[p * M + row] = s2;

#pragma unroll
    for (int b2 = 0; b2 < 2; ++b2) {
        const int o = kc * 2 + b2;       // global k-octet
        const int s = o >> 2;
        const int g = o & 3;
        const int l = row16 + 16 * g;
        f16x8 hv, lv;
#pragma unroll
        for (int j = 0; j < 8; ++j) {
            float x = v[b2 * 8 + j];
            _Float16 h = (_Float16)x;
            hv[j] = h;
            lv[j] = (_Float16)(x - (float)h);
        }
        size_t base = ((((size_t)(p * 8 + s) * 16 + t16) * 2 + 0) * 64 + l) * 8;
        *(f16x8*)(Ffrag + base)         = hv;   // h=0
        *(f16x8*)(Ffrag + base + 512)   = lv;   // h=1 (+1*64*8)
    }
}

// ======================= fused dist (MFMA) + mining =======================
#define PITCH 258
__global__ __launch_bounds__(512) void k_dist(const _Float16* __restrict__ Ffrag,
                                              const float* __restrict__ x2g,
                                              const int* __restrict__ label,
                                              float* __restrict__ recs)
{
    __shared__ __align__(16) float region[32 * PITCH];   // dist tile, 33,024 B
    __shared__ float fullS[8][NNEG];
    __shared__ float fullC[8][NNEG];
    __shared__ float posbuf[8][NPOS];
    __shared__ float wred[16];

    const int bxr = blockIdx.x;                       // 496 = 8 XCD * 62
    const int swz = (bxr & 7) * 62 + (bxr >> 3);      // bijective; part's 8 tiles same-XCD
    const int p   = swz >> 3;
    const int ib  = (swz & 7) * 32;                   // anchor base
    const int t   = threadIdx.x;
    const int lane = t & 63;
    const int w    = t >> 6;                          // wave 0..7

    const int a0 = (swz & 7) * 2;                     // first A row-tile (of 16)

    f32x4 acc[2][2];
#pragma unroll
    for (int rt = 0; rt < 2; ++rt)
#pragma unroll
        for (int c = 0; c < 2; ++c) acc[rt][c] = (f32x4){0.f, 0.f, 0.f, 0.f};

    const _Float16* Pbase = Ffrag + (size_t)p * 131072 + lane * 8;  // 8 s-slabs * 16384

    auto LOAD = [&](int s, f16x8 (&A)[2][2], f16x8 (&B)[2][2]) {
        const _Float16* SB = Pbase + s * 16384;
#pragma unroll
        for (int rt = 0; rt < 2; ++rt)
#pragma unroll
            for (int h = 0; h < 2; ++h)
                A[rt][h] = *(const f16x8*)(SB + ((a0 + rt) * 2 + h) * 512);
#pragma unroll
        for (int c = 0; c < 2; ++c)
#pragma unroll
            for (int h = 0; h < 2; ++h)
                B[c][h] = *(const f16x8*)(SB + ((w * 2 + c) * 2 + h) * 512);
    };

    // ---- barrier-free MFMA K-loop, s+1 prefetched under s's MFMAs ----
    f16x8 cA[2][2], cB[2][2], nA[2][2], nB[2][2];
    LOAD(0, cA, cB);
#pragma unroll
    for (int s = 0; s < 8; ++s) {
        if (s < 7) LOAD(s + 1, nA, nB);
#pragma unroll
        for (int rt = 0; rt < 2; ++rt)
#pragma unroll
            for (int c = 0; c < 2; ++c) {
                acc[rt][c] = __builtin_amdgcn_mfma_f32_16x16x32_f16(cA[rt][0], cB[c][0], acc[rt][c], 0, 0, 0);
                acc[rt][c] = __builtin_amdgcn_mfma_f32_16x16x32_f16(cA[rt][0], cB[c][1], acc[rt][c], 0, 0, 0);
                acc[rt][c] = __builtin_amdgcn_mfma_f32_16x16x32_f16(cA[rt][1], cB[c][0], acc[rt][c], 0, 0, 0);
            }
        if (s < 7) {
#pragma unroll
            for (int rt = 0; rt < 2; ++rt)
#pragma unroll
                for (int h = 0; h < 2; ++h) { cA[rt][h] = nA[rt][h]; }
#pragma unroll
            for (int c = 0; c < 2; ++c)
#pragma unroll
                for (int h = 0; h < 2; ++h) { cB[c][h] = nB[c][h]; }
        }
    }

    // ---- epilogue: dist -> LDS (C/D layout: col=lane&15, row=(lane>>4)*4+r) ----
    const int cbase = lane & 15;
    const int rbase = (lane >> 4) * 4;
    float xi[2][4], xj[2];
#pragma unroll
    for (int rt = 0; rt < 2; ++rt)
#pragma unroll
        for (int r = 0; r < 4; ++r)
            xi[rt][r] = x2g[p * M + ib + rt * 16 + rbase + r];
#pragma unroll
    for (int c = 0; c < 2; ++c)
        xj[c] = x2g[p * M + (w * 2 + c) * 16 + cbase];

#pragma unroll
    for (int rt = 0; rt < 2; ++rt)
#pragma unroll
        for (int c = 0; c < 2; ++c)
#pragma unroll
            for (int r = 0; r < 4; ++r) {
                float d2 = xi[rt][r] + xj[c] - 2.f * acc[rt][c][r];
                float dd = sqrtf(fmaxf(d2, 0.f) + 1e-12f);
                region[(rt * 16 + rbase + r) * PITCH + (w * 2 + c) * 16 + cbase] = dd;
            }
    __syncthreads();

    // ---- mining: wave-private (wave w owns anchors w*4..w*4+3) ----
    int llab[4];
#pragma unroll
    for (int ch = 0; ch < 4; ++ch) llab[ch] = label[p * M + ch * 64 + lane];

    for (int idx = lane; idx < NNEG; idx += 64) { fullS[w][idx] = 0.f; fullC[w][idx] = 0.f; }

    const unsigned long long lmask = (1ull << lane) - 1ull;
    float hardAcc = 0.f, rowSum = 0.f;

    for (int a = 0; a < 4; ++a) {
        const int ii = w * 4 + a;
        const int li = label[p * M + ib + ii];   // wave-uniform
        int runMatch = 0;
        float negmin = 3.4e38f;
        float ndv[4]; int nqv[4]; int nval[4];
#pragma unroll
        for (int ch = 0; ch < 4; ++ch) {
            const int j = ch * 64 + lane;
            float d = region[ii * PITCH + j];
            bool match = (llab[ch] == li);
            unsigned long long bal = __ballot(match);
            int posRank = runMatch + __popcll(bal & lmask);
            if (match) {
                if (posRank < NPOS) posbuf[w][posRank] = d;
                nval[ch] = 0; ndv[ch] = 0.f; nqv[ch] = 0;
            } else {
                ndv[ch] = d; nqv[ch] = j - posRank; nval[ch] = 1;
                negmin = fminf(negmin, d);
            }
            runMatch += __popcll(bal);
            rowSum += d;
        }
        asm volatile("s_waitcnt lgkmcnt(0)" ::: "memory");  // same-wave posbuf drain

        float maxpos = posbuf[w][0];
#pragma unroll
        for (int pp = 1; pp < NPOS; ++pp) maxpos = fmaxf(maxpos, posbuf[w][pp]);
#pragma unroll
        for (int off = 32; off >= 1; off >>= 1)
            negmin = fminf(negmin, __shfl_xor(negmin, off));
        hardAcc += fmaxf(MARG + maxpos - negmin, 0.f);

#pragma unroll
        for (int ch = 0; ch < 4; ++ch) {
            if (nval[ch]) {
                float dneg = ndv[ch]; int q = nqv[ch];
                float s = 0.f, cnt = 0.f;
#pragma unroll
                for (int pp = 0; pp < NPOS; ++pp) {
                    float v = MARG + posbuf[w][pp] - dneg;
                    if (v > 0.f) { s += v; cnt += 1.f; }
                }
                fullS[w][q] += s;   // per-wave private; q distinct per lane
                fullC[w][q] += cnt;
            }
        }
    }

#pragma unroll
    for (int off = 32; off >= 1; off >>= 1) rowSum += __shfl_xor(rowSum, off);
    if (lane == 0) { wred[w] = hardAcc; wred[8 + w] = rowSum; }
    __syncthreads();

    float* rec = recs + (size_t)swz * REC;
    if (t < NNEG) {
        float s = 0.f, c = 0.f;
#pragma unroll
        for (int v = 0; v < 8; ++v) { s += fullS[v][t]; c += fullC[v][t]; }
        rec[t] = s;
        rec[NNEG + t] = c;
    }
    if (t == 0) {
        float h = 0.f, ds = 0.f;
#pragma unroll
        for (int v = 0; v < 8; ++v) { h += wred[v]; ds += wred[8 + v]; }
        rec[496] = h;
        rec[497] = ds;
    }
}

// ======================= finalize =======================
__global__ __launch_bounds__(256) void k_fin1(const float* __restrict__ recs,
                                              float* __restrict__ out,
                                              float* __restrict__ wsP)
{
    const int p = blockIdx.x;
    const int t = threadIdx.x;
    if (t < NNEG) {
        float s = 0.f, c = 0.f;
        for (int a = 0; a < 8; ++a) {
            const float* rec = recs + (size_t)(p * 8 + a) * REC;
            s += rec[t];
            c += rec[NNEG + t];
        }
        out[p * NNEG + t]          = s / (c + 1e-6f);
        out[OFF_FN + p * NNEG + t] = c;
    }
    if (t == 0) {
        float h = 0.f, ds = 0.f;
        for (int a = 0; a < 8; ++a) {
            const float* rec = recs + (size_t)(p * 8 + a) * REC;
            h  += rec[496];
            ds += rec[497];
        }
        out[OFF_HARD + p] = h * (1.0f / 256.0f);
        wsP[p] = ds;
    }
}

__global__ void k_fin2(const float* __restrict__ wsP, float* __restrict__ out)
{
    int t = threadIdx.x;
    float v = (t < NPART) ? wsP[t] : 0.f;
#pragma unroll
    for (int off = 32; off >= 1; off >>= 1) v += __shfl_xor(v, off);
    if (t == 0) out[OFF_MD] = v / (float)((size_t)NPART * M * M);
}

// ======================= fallback: proven round-1 fused path =======================
__global__ __launch_bounds__(256) void fb_main(
    const float* __restrict__ F, const int* __restrict__ label, float* __restrict__ ws)
{
    __shared__ __align__(16) float region[256 * 36];
    __shared__ float x2s[M];
    __shared__ int   lab[M];
    __shared__ float posbuf[4][NPOS];
    __shared__ float fullS[4][NNEG];
    __shared__ float fullC[4][NNEG];
    __shared__ float wred[8];

    const int bx = blockIdx.x;
    const int p  = bx >> 3;
    const int ib = (bx & 7) * 32;
    const int t  = threadIdx.x;

    lab[t] = label[p * M + t];
    for (int idx = t; idx < 4 * NNEG; idx += 256) {
        (&fullS[0][0])[idx] = 0.f;
        (&fullC[0][0])[idx] = 0.f;
    }
    __syncthreads();

    const float4* Fv = (const float4*)(F + (size_t)p * (M * DD));

    float acc[4][8];
#pragma unroll
    for (int r = 0; r < 4; ++r)
#pragma unroll
        for (int c = 0; c < 8; ++c) acc[r][c] = 0.f;

    float x2loc = 0.f;
    const int tc = t & 31;
    const int tg = t >> 5;

    for (int kt = 0; kt < 8; ++kt) {
#pragma unroll
        for (int w = 0; w < 8; ++w) {
            int ch = w * 256 + t;
            int r  = ch >> 3;
            int q  = ch & 7;
            float4 v = Fv[r * 64 + kt * 8 + q];
            float* dst = &region[r * 36 + q * 4];
            dst[0] = v.x; dst[1] = v.y; dst[2] = v.z; dst[3] = v.w;
        }
        __syncthreads();
#pragma unroll
        for (int k4 = 0; k4 < 8; ++k4) {
            float4 b = *(const float4*)&region[t * 36 + k4 * 4];
            x2loc += b.x * b.x + b.y * b.y + b.z * b.z + b.w * b.w;
        }
#pragma unroll
        for (int k4 = 0; k4 < 8; ++k4) {
            float4 a4[4], b4[8];
#pragma unroll
            for (int r = 0; r < 4; ++r)
                a4[r] = *(const float4*)&region[(ib + tg * 4 + r) * 36 + k4 * 4];
#pragma unroll
            for (int c = 0; c < 8; ++c)
                b4[c] = *(const float4*)&region[(tc + 32 * c) * 36 + k4 * 4];
#pragma unroll
            for (int r = 0; r < 4; ++r)
#pragma unroll
                for (int c = 0; c < 8; ++c)
                    acc[r][c] += a4[r].x * b4[c].x + a4[r].y * b4[c].y +
                                 a4[r].z * b4[c].z + a4[r].w * b4[c].w;
        }
        __syncthreads();
    }

    x2s[t] = x2loc;
    __syncthreads();

#pragma unroll
    for (int r = 0; r < 4; ++r) {
        int ii = tg * 4 + r;
        float xi = x2s[ib + ii];
#pragma unroll
        for (int c = 0; c < 8; ++c) {
            int j = tc + 32 * c;
            float d2 = xi + x2s[j] - 2.f * acc[r][c];
            region[ii * M + j] = sqrtf(fmaxf(d2, 0.f) + 1e-12f);
        }
    }
    __syncthreads();

    const int lane = t & 63;
    const int w    = t >> 6;
    const unsigned long long lmask = (1ull << lane) - 1ull;

    float hardAcc = 0.f;
    float rowSum  = 0.f;

    for (int a = 0; a < 8; ++a) {
        int ii = w * 8 + a;
        int li = lab[ib + ii];
        int runMatch = 0;
        float negmin = 3.4e38f;
        float ndv[4]; int nqv[4]; int nval[4];
#pragma unroll
        for (int ch = 0; ch < 4; ++ch) {
            int j = ch * 64 + lane;
            float d = region[ii * M + j];
            bool match = (lab[j] == li);
            unsigned long long bal = __ballot(match);
            int prefix  = __popcll(bal & lmask);
            int posRank = runMatch + prefix;
            if (match) {
                if (posRank < NPOS) posbuf[w][posRank] = d;
                nval[ch] = 0; ndv[ch] = 0.f; nqv[ch] = 0;
            } else {
                ndv[ch] = d; nqv[ch] = j - posRank; nval[ch] = 1;
                negmin = fminf(negmin, d);
            }
            runMatch += __popcll(bal);
            rowSum += d;
        }
        __syncthreads();

        float maxpos = posbuf[w][0];
#pragma unroll
        for (int pp = 1; pp < NPOS; ++pp) maxpos = fmaxf(maxpos, posbuf[w][pp]);
#pragma unroll
        for (int off = 32; off >= 1; off >>= 1)
            negmin = fminf(negmin, __shfl_xor(negmin, off));
        hardAcc += fmaxf(MARG + maxpos - negmin, 0.f);

#pragma unroll
        for (int ch = 0; ch < 4; ++ch) {
            if (nval[ch]) {
                float dneg = ndv[ch]; int q = nqv[ch];
                float s = 0.f, cnt = 0.f;
#pragma unroll
                for (int pp = 0; pp < NPOS; ++pp) {
                    float v = MARG + posbuf[w][pp] - dneg;
                    if (v > 0.f) { s += v; cnt += 1.f; }
                }
                fullS[w][q] += s;
                fullC[w][q] += cnt;
            }
        }
        __syncthreads();
    }

#pragma unroll
    for (int off = 32; off >= 1; off >>= 1) rowSum += __shfl_xor(rowSum, off);
    if (lane == 0) { wred[w] = hardAcc; wred[4 + w] = rowSum; }
    __syncthreads();

    float* rec = ws + (size_t)bx * REC;
    if (t < NNEG) {
        float s = fullS[0][t] + fullS[1][t] + fullS[2][t] + fullS[3][t];
        float c = fullC[0][t] + fullC[1][t] + fullC[2][t] + fullC[3][t];
        rec[t] = s;
        rec[NNEG + t] = c;
    }
    if (t == 0) {
        rec[496] = wred[0] + wred[1] + wred[2] + wred[3];
        rec[497] = wred[4] + wred[5] + wred[6] + wred[7];
    }
}

// ======================= launch =======================
extern "C" void kernel_launch(void* const* d_in, const int* in_sizes, int n_in,
                              void* d_out, int out_size, void* d_ws, size_t ws_size,
                              hipStream_t stream)
{
    const float* F     = (const float*)d_in[0];
    const int*   label = (const int*)d_in[1];
    float*       ws    = (float*)d_ws;
    float*       out   = (float*)d_out;

    if (ws_size >= WS_NEED) {
        _Float16* Ffrag = (_Float16*)ws;
        float*    x2g   = ws + X0;
        float*    recs  = ws + R0;
        float*    wsP   = ws + P0;
        k_split<<<dim3(992),   dim3(256), 0, stream>>>(F, Ffrag, x2g);
        k_dist <<<dim3(496),   dim3(512), 0, stream>>>(Ffrag, x2g, label, recs);
        k_fin1 <<<dim3(NPART), dim3(256), 0, stream>>>(recs, out, wsP);
        k_fin2 <<<dim3(1),     dim3(64),  0, stream>>>(wsP, out);
    } else {
        float* wsP = ws + (size_t)496 * REC;
        fb_main<<<dim3(496),   dim3(256), 0, stream>>>(F, label, ws);
        k_fin1 <<<dim3(NPART), dim3(256), 0, stream>>>(ws, out, wsP);
        k_fin2 <<<dim3(1),     dim3(64),  0, stream>>>(wsP, out);
    }
}